// Round 15
// baseline (110.779 us; speedup 1.0000x reference)
//
#include <hip/hip_runtime.h>
#include <math.h>

// Fully-fused 2-layer Mamba-ish block (L=1 => tokens independent end-to-end).
// MFMA bf16; weights pre-packed to B-fragment layout in d_ws by prep_kernel.
// History: R10=43.8us / R13=41.9us at 2 waves/SIMD (waves_per_eu(2,2), 256 VGPR).
// R8/R9/R14 all FAILED trying >2 waves/SIMD: allocator picks 64-128 VGPR and
// spills (WRITE_SIZE 20-65MB). R15: raise arithmetic intensity instead of TLP:
// TPB=32 (two 16-token M-groups, 100 blocks). Every B-fragment load now feeds
// TWO MFMAs; aggregate weight traffic halves. GEMM1: 8 nf/wave, acc 16xf32x4 +
// 2-deep 8-frag pipeline (~170 VGPR peak, fits 256 license). xnp unioned with
// dbl (LDS 115KB < 160KB; 67KB precedent). bc computed wave-locally
// (2 lanes/token). lds_barrier (lgkmcnt-only) kept. Spill tell: WRITE_SIZE=3200KB.

#define NTOK 3200
#define DM   256
#define DI   512
#define NX   1024
#define DTR  16
#define DS   64
#define NPJ  144
#define TPB  32
#define THR  512

#define PK1 (64*8*64*8)    // W1 packed elems/layer (256x1024)
#define PK2 (9*16*64*8)    // W2 (512x144)
#define PK3 (16*16*64*8)   // W3 (512x256)
#define PK4 (32*64*8)      // W4 dtproj (16x512, K zero-padded to 32)

using short8 = __attribute__((ext_vector_type(8))) short;
using f32x4  = __attribute__((ext_vector_type(4))) float;

__device__ __forceinline__ float siluf(float x){
    return x * __builtin_amdgcn_rcpf(1.0f + __expf(-x));
}
__device__ __forceinline__ float softplusf(float x){
    return (x > 15.f) ? x : __logf(1.0f + __expf(x));
}

__device__ __forceinline__ unsigned short f2bf(float f){
    unsigned int u = __float_as_uint(f);
    u += 0x7FFFu + ((u>>16)&1u);           // RNE
    return (unsigned short)(u>>16);
}
__device__ __forceinline__ float bf2f(unsigned short h){
    return __uint_as_float(((unsigned int)h)<<16);
}
// element index into packed-A LDS [ks][64 lanes][8] (one 16-token group)
__device__ __forceinline__ int apos(int m, int k){
    return (((k>>5)*64) + (m&15) + (((k&31)>>3)<<4))*8 + (k&7);
}
// LDS-only barrier: order ds ops, do NOT drain vmcnt (weight loads keep flying).
// Safe because no global writes happen inside the layer loop.
__device__ __forceinline__ void lds_barrier(){
    asm volatile("s_waitcnt lgkmcnt(0)" ::: "memory");
    __builtin_amdgcn_s_barrier();
}

// ---------------- prep: pack weights to bf16 B-fragment layout ----------------
// frags/layer: [0,512) W1, [512,656) W2, [656,912) W3, [912,944) W4.
__global__ __launch_bounds__(256) void prep_kernel(
    const float* __restrict__ in_w, const float* __restrict__ xw,
    const float* __restrict__ ow,   const float* __restrict__ dtw,
    unsigned short* __restrict__ ws)
{
    const int gid  = blockIdx.x*256 + threadIdx.x;
    const int lane = gid & 63;
    const int fr   = (gid>>6) % 944;
    const int l    = (gid>>6) / 944;
    unsigned short* W1p = ws;
    unsigned short* W2p = ws + 2*PK1;
    unsigned short* W3p = ws + 2*PK1 + 2*PK2;
    unsigned short* W4p = ws + 2*PK1 + 2*PK2 + 2*PK3;

    if (fr >= 912){   // W4: dtproj, K=16 zero-padded to 32
        const int nf = fr - 912;
        const float* src = dtw + (size_t)l*DTR*DI;
        const int n = nf*16 + (lane&15);
        short8 v;
        #pragma unroll
        for (int j=0;j<8;j++){
            const int k = (lane>>4)*8 + j;
            v[j] = (k < DTR) ? (short)f2bf(src[(size_t)k*DI + n]) : (short)0;
        }
        *(short8*)(W4p + (size_t)l*PK4 + ((size_t)nf*64 + lane)*8) = v;
        return;
    }
    const float* src; unsigned short* dst; int N, nf, ks;
    if (fr < 512){
        src = in_w + (size_t)l*DM*NX; N = NX; nf = fr>>3; ks = fr&7;
        dst = W1p + (size_t)l*PK1 + ((size_t)fr*64 + lane)*8;
    } else if (fr < 656){
        const int f2 = fr-512;
        src = xw + (size_t)l*DI*NPJ; N = NPJ; nf = f2>>4; ks = f2&15;
        dst = W2p + (size_t)l*PK2 + ((size_t)f2*64 + lane)*8;
    } else {
        const int f3 = fr-656;
        src = ow + (size_t)l*DI*DM; N = DM; nf = f3>>4; ks = f3&15;
        dst = W3p + (size_t)l*PK3 + ((size_t)f3*64 + lane)*8;
    }
    const int k0 = ks*32 + (lane>>4)*8;
    const int n  = nf*16 + (lane&15);
    short8 v;
    #pragma unroll
    for (int j=0;j<8;j++) v[j] = (short)f2bf(src[(size_t)(k0+j)*N + n]);
    *(short8*)dst = v;
}

union LU {
    unsigned short xnp[2][8*64*8];   // A-pack xn, 2 groups (16 KB)
    float dbl[TPB][NPJ+4];           // GEMM2 output fp32 (18.9 KB)
};

// GEMM1 macros: slot kk in 0..7; 8 nf/wave; each B-frag feeds 2 MFMAs.
#define G1_LOAD(buf, kk) { \
    _Pragma("unroll") \
    for (int i=0;i<8;i++) \
        buf[i] = *(const short8*)(W1l + (((size_t)(nf0+i)*8 + (kk))*64 + lane)*8); }
#define G1_MFMA(buf, kk) { \
    const short8 a0 = *(const short8*)&u.xnp[0][((kk)*64+lane)*8]; \
    const short8 a1 = *(const short8*)&u.xnp[1][((kk)*64+lane)*8]; \
    _Pragma("unroll") \
    for (int i=0;i<8;i++){ \
        accA[i] = __builtin_amdgcn_mfma_f32_16x16x32_bf16(a0, buf[i], accA[i], 0,0,0); \
        accB[i] = __builtin_amdgcn_mfma_f32_16x16x32_bf16(a1, buf[i], accB[i], 0,0,0); } }

// ---------------- fused network kernel ----------------
__global__ __launch_bounds__(THR)
__attribute__((amdgpu_waves_per_eu(2,2)))
void fused_net_kernel(
    const float* __restrict__ x,
    const float* __restrict__ ln_w, const float* __restrict__ ln_b,
    const float* __restrict__ in_b,
    const float* __restrict__ cw,   const float* __restrict__ cb,
    const float* __restrict__ dtb,
    const float* __restrict__ Dp,   const float* __restrict__ ob,
    const unsigned short* __restrict__ wsp,
    float* __restrict__ outp)
{
    __shared__ __align__(16) float h[TPB][DM+4];             // 33.3 KB residual
    __shared__ __align__(16) LU u;                           // 18.9 KB
    __shared__ __align__(16) unsigned short xcp[2][16*64*8]; // 32 KB xc / y
    __shared__ __align__(16) unsigned short sgs[TPB][DI];    // 32 KB silu(gate)

    const int tid  = threadIdx.x;
    const int lane = tid & 63;
    const int wv   = tid >> 6;          // 0..7
    const int t0   = blockIdx.x * TPB;

    const unsigned short* W1p = wsp;
    const unsigned short* W2p = wsp + 2*PK1;
    const unsigned short* W3p = wsp + 2*PK1 + 2*PK2;
    const unsigned short* W4p = wsp + 2*PK1 + 2*PK2 + 2*PK3;

    // ---- load residual tile (32 x 256 fp32): 2048 float4 ----
    #pragma unroll
    for (int i=0;i<4;i++){
        const int f4 = tid + i*THR;
        const int t = f4>>6, c4 = f4&63;
        *(float4*)&h[t][c4*4] = *(const float4*)(x + (size_t)(t0+t)*DM + c4*4);
    }
    __syncthreads();

    for (int l=0; l<2; ++l){
        const float* lwl = ln_w + l*DM;
        const float* lbl = ln_b + l*DM;
        const float* b1  = in_b + l*NX;
        const float* cw3 = cw + l*4*DI + 3*DI;
        const float* cbv = cb + l*DI;
        const float* bdl = dtb + l*DI;
        const float* Dl  = Dp + l*DI;
        const float* b3  = ob + l*DM;
        const unsigned short* W1l = W1p + (size_t)l*PK1;
        const unsigned short* W2l = W2p + (size_t)l*PK2;
        const unsigned short* W3l = W3p + (size_t)l*PK3;
        const unsigned short* W4l = W4p + (size_t)l*PK4;

        // ---- Phase 1: LayerNorm; 16 threads/token, 16 elems each ----
        {
            const int t = tid>>4, q = tid&15, c0 = q*16;
            float a[16];
            #pragma unroll
            for (int f=0;f<4;f++)
                *(float4*)&a[f*4] = *(float4*)&h[t][c0+f*4];
            float s = 0.f;
            #pragma unroll
            for (int i=0;i<16;i++) s += a[i];
            #pragma unroll
            for (int o=8;o>=1;o>>=1) s += __shfl_xor(s, o, 16);
            const float mu = s*(1.0f/DM);
            float q2 = 0.f;
            #pragma unroll
            for (int i=0;i<16;i++){ a[i] -= mu; q2 += a[i]*a[i]; }
            #pragma unroll
            for (int o=8;o>=1;o>>=1) q2 += __shfl_xor(q2, o, 16);
            const float r = rsqrtf(q2*(1.0f/DM)+1e-5f);
            const int grp = t>>4, tl = t&15;
            #pragma unroll
            for (int i=0;i<16;i++){
                const int c = c0+i;
                u.xnp[grp][apos(tl,c)] = f2bf(a[i]*r*lwl[c] + lbl[c]);
            }
        }
        lds_barrier();

        // ---- Phase 2: GEMM1 (32x1024, K=256); 8 nf/wave; 2-deep pipeline ----
        {
            const int nf0 = wv*8;
            const bool isx = (wv < 4);     // waves 0-3: xc cols, 4-7: gate cols
            f32x4 accA[8], accB[8];
            #pragma unroll
            for (int i=0;i<8;i++){ accA[i]=f32x4{0.f,0.f,0.f,0.f}; accB[i]=f32x4{0.f,0.f,0.f,0.f}; }

            short8 bA[8], bB[8];
            G1_LOAD(bA, 0);
            G1_LOAD(bB, 1);
            G1_MFMA(bA, 0);
            G1_LOAD(bA, 2);
            G1_MFMA(bB, 1);
            G1_LOAD(bB, 3);
            G1_MFMA(bA, 2);
            G1_LOAD(bA, 4);
            G1_MFMA(bB, 3);
            G1_LOAD(bB, 5);
            G1_MFMA(bA, 4);
            G1_LOAD(bA, 6);
            G1_MFMA(bB, 5);
            G1_LOAD(bB, 7);
            G1_MFMA(bA, 6);
            G1_MFMA(bB, 7);

            #pragma unroll
            for (int i=0;i<8;i++){
                const int col = (nf0+i)*16 + (lane&15);
                const float b1v = b1[col];
                if (isx){
                    const float cwv = cw3[col], cbb = cbv[col];
                    #pragma unroll
                    for (int r=0;r<4;r++){
                        const int tl = (lane>>4)*4 + r;
                        xcp[0][apos(tl,col)] = f2bf(siluf((accA[i][r]+b1v)*cwv + cbb));
                        xcp[1][apos(tl,col)] = f2bf(siluf((accB[i][r]+b1v)*cwv + cbb));
                    }
                } else {
                    #pragma unroll
                    for (int r=0;r<4;r++){
                        const int tl = (lane>>4)*4 + r;
                        sgs[tl][col-DI]    = f2bf(siluf(accA[i][r]+b1v));
                        sgs[16+tl][col-DI] = f2bf(siluf(accB[i][r]+b1v));
                    }
                }
            }
        }
        lds_barrier();

        // ---- Phase 3: GEMM2 (32x144, K=512) -> dbl; wave wv: nf=wv (+8 for wv0) ----
        for (int nf = wv; nf < 9; nf += 8){
            f32x4 accA = f32x4{0.f,0.f,0.f,0.f};
            f32x4 accB = f32x4{0.f,0.f,0.f,0.f};
            #pragma unroll 8
            for (int ks=0;ks<16;ks++){
                const short8 b  = *(const short8*)(W2l + (((size_t)nf*16 + ks)*64 + lane)*8);
                const short8 a0 = *(const short8*)&xcp[0][(ks*64+lane)*8];
                const short8 a1 = *(const short8*)&xcp[1][(ks*64+lane)*8];
                accA = __builtin_amdgcn_mfma_f32_16x16x32_bf16(a0, b, accA, 0,0,0);
                accB = __builtin_amdgcn_mfma_f32_16x16x32_bf16(a1, b, accB, 0,0,0);
            }
            const int col = nf*16 + (lane&15);
            #pragma unroll
            for (int r=0;r<4;r++){
                u.dbl[(lane>>4)*4 + r][col]      = accA[r];
                u.dbl[16 + (lane>>4)*4 + r][col] = accB[r];
            }
        }
        lds_barrier();

        // ---- Phase 5: bc (2 lanes/token) + dt-proj MFMA + y (in-place xcp) ----
        {
            const int btok = lane>>1, half = lane&1;   // 32 states per lane
            float p = 0.f;
            #pragma unroll
            for (int f=0; f<8; f++){
                const float4 bv = *(const float4*)&u.dbl[btok][DTR + half*32 + f*4];
                const float4 cv = *(const float4*)&u.dbl[btok][DTR + DS + half*32 + f*4];
                p += bv.x*cv.x + bv.y*cv.y + bv.z*cv.z + bv.w*cv.w;
            }
            p += __shfl_xor(p, 1, 64);     // lane 2t,2t+1 hold bc[t]
            const int m = lane&15, kg = lane>>4;
            float bctA[4], bctB[4];
            #pragma unroll
            for (int r=0;r<4;r++){
                bctA[r] = __shfl(p, (kg*4+r)*2, 64);
                bctB[r] = __shfl(p, (16+kg*4+r)*2, 64);
            }
            short8 a0, a1;
            #pragma unroll
            for (int j=0;j<8;j++){
                const int k = kg*8 + j;
                a0[j] = (k < DTR) ? (short)f2bf(u.dbl[m][k])    : (short)0;
                a1[j] = (k < DTR) ? (short)f2bf(u.dbl[16+m][k]) : (short)0;
            }
            #pragma unroll
            for (int i=0;i<4;i++){
                const int nf = wv*4 + i;    // 8 waves x 4 = 32 tiles
                const short8 b = *(const short8*)(W4l + ((size_t)nf*64 + lane)*8);
                f32x4 accA = f32x4{0.f,0.f,0.f,0.f};
                f32x4 accB = f32x4{0.f,0.f,0.f,0.f};
                accA = __builtin_amdgcn_mfma_f32_16x16x32_bf16(a0, b, accA, 0,0,0);
                accB = __builtin_amdgcn_mfma_f32_16x16x32_bf16(a1, b, accB, 0,0,0);
                const int c = nf*16 + (lane&15);
                const float bdv = bdl[c], Dv = Dl[c];
                #pragma unroll
                for (int r=0;r<4;r++){
                    const int tl = kg*4 + r;
                    const int ip = apos(tl,c);
                    const float dtA = softplusf(accA[r] + bdv);
                    xcp[0][ip] = f2bf(bf2f(xcp[0][ip])*(dtA*bctA[r] + Dv)*bf2f(sgs[tl][c]));
                    const float dtB = softplusf(accB[r] + bdv);
                    xcp[1][ip] = f2bf(bf2f(xcp[1][ip])*(dtB*bctB[r] + Dv)*bf2f(sgs[16+tl][c]));
                }
            }
        }
        lds_barrier();

        // ---- Phase 6: GEMM3 (32x256, K=512) + bias + residual -> h ----
        #pragma unroll
        for (int ni=0;ni<2;ni++){
            const int nf = wv*2 + ni;      // 8 waves x 2 = 16 tiles
            f32x4 accA = f32x4{0.f,0.f,0.f,0.f};
            f32x4 accB = f32x4{0.f,0.f,0.f,0.f};
            #pragma unroll 8
            for (int ks=0;ks<16;ks++){
                const short8 b  = *(const short8*)(W3l + (((size_t)nf*16 + ks)*64 + lane)*8);
                const short8 a0 = *(const short8*)&xcp[0][(ks*64+lane)*8];
                const short8 a1 = *(const short8*)&xcp[1][(ks*64+lane)*8];
                accA = __builtin_amdgcn_mfma_f32_16x16x32_bf16(a0, b, accA, 0,0,0);
                accB = __builtin_amdgcn_mfma_f32_16x16x32_bf16(a1, b, accB, 0,0,0);
            }
            const int col = nf*16 + (lane&15);
            const float bo = b3[col];
            #pragma unroll
            for (int r=0;r<4;r++){
                const int tl = (lane>>4)*4 + r;
                h[tl][col]    = accA[r] + bo + h[tl][col];
                h[16+tl][col] = accB[r] + bo + h[16+tl][col];
            }
        }
        lds_barrier();
    }

    // ---- store final hidden: 2048 float4 ----
    #pragma unroll
    for (int i=0;i<4;i++){
        const int f4 = tid + i*THR;
        const int t = f4>>6, c4 = f4&63;
        *(float4*)(outp + (size_t)(t0+t)*DM + c4*4) = *(float4*)&h[t][c4*4];
    }
}

extern "C" void kernel_launch(void* const* d_in, const int* in_sizes, int n_in,
                              void* d_out, int out_size, void* d_ws, size_t ws_size,
                              hipStream_t stream)
{
    const float* x    = (const float*)d_in[0];
    const float* ln_w = (const float*)d_in[1];
    const float* ln_b = (const float*)d_in[2];
    const float* in_w = (const float*)d_in[3];
    const float* in_b = (const float*)d_in[4];
    const float* cw   = (const float*)d_in[5];
    const float* cb   = (const float*)d_in[6];
    const float* xw   = (const float*)d_in[7];
    const float* dtw  = (const float*)d_in[8];
    const float* dtb  = (const float*)d_in[9];
    // d_in[10] = A_log: unused (L==1, scan starts at h0=0)
    const float* Dp   = (const float*)d_in[11];
    const float* ow   = (const float*)d_in[12];
    const float* ob   = (const float*)d_in[13];
    float* outp = (float*)d_out;
    unsigned short* wsp = (unsigned short*)d_ws;

    // pack weights: 2 layers x 944 frags x 64 lanes = 120832 threads
    prep_kernel<<<472, 256, 0, stream>>>(in_w, xw, ow, dtw, wsp);
    fused_net_kernel<<<NTOK/TPB, THR, 0, stream>>>(
        x, ln_w, ln_b, in_b, cw, cb, dtb, Dp, ob, wsp, outp);
}

// Round 16
// 56.020 us; speedup vs baseline: 1.9775x; 1.9775x over previous
//
#include <hip/hip_runtime.h>
#include <math.h>

// Fully-fused 2-layer Mamba-ish block (L=1 => tokens independent end-to-end).
// MFMA bf16; weights pre-packed to B-fragment layout in d_ws by prep_kernel.
// History: R13=41.9us best (512thr, 2 waves/SIMD, cross-phase reg prefetch,
// lgkmcnt-only barrier). R8/R9/R12/R14/R15 all FAILED the same way: allocator
// pins 128 VGPR; any structure with peak-live >128 spills (WRITE_SIZE 20-65MB).
// Per-block weight stream (1.9MB) is TPB-invariant => tiling can't reduce it.
// R16: consolidation = exact R13 + GEMM2 9th-tile K-split across waves 0/1
// (removes wave-0 serial double duty; partials in dbl[.][128+]+dbl2, bc adds
// them for bq==3 lanes). Spill tell: WRITE_SIZE must stay 3200 KB.

#define NTOK 3200
#define DM   256
#define DI   512
#define NX   1024
#define DTR  16
#define DS   64
#define NPJ  144
#define TPB  16
#define THR  512

#define PK1 (64*8*64*8)    // W1 packed elems/layer (256x1024)
#define PK2 (9*16*64*8)    // W2 (512x144)
#define PK3 (16*16*64*8)   // W3 (512x256)
#define PK4 (32*64*8)      // W4 dtproj (16x512, K zero-padded to 32)

using short8 = __attribute__((ext_vector_type(8))) short;
using f32x4  = __attribute__((ext_vector_type(4))) float;

__device__ __forceinline__ float siluf(float x){
    return x * __builtin_amdgcn_rcpf(1.0f + __expf(-x));
}
__device__ __forceinline__ float softplusf(float x){
    return (x > 15.f) ? x : __logf(1.0f + __expf(x));
}

__device__ __forceinline__ unsigned short f2bf(float f){
    unsigned int u = __float_as_uint(f);
    u += 0x7FFFu + ((u>>16)&1u);           // RNE
    return (unsigned short)(u>>16);
}
__device__ __forceinline__ float bf2f(unsigned short h){
    return __uint_as_float(((unsigned int)h)<<16);
}
// element index into packed-A LDS [ks][64 lanes][8]
__device__ __forceinline__ int apos(int m, int k){
    return (((k>>5)*64) + (m&15) + (((k&31)>>3)<<4))*8 + (k&7);
}
// LDS-only barrier: order ds ops, do NOT drain vmcnt (weight loads keep flying).
// Safe because no global writes happen inside the layer loop.
__device__ __forceinline__ void lds_barrier(){
    asm volatile("s_waitcnt lgkmcnt(0)" ::: "memory");
    __builtin_amdgcn_s_barrier();
}

// ---------------- prep: pack weights to bf16 B-fragment layout ----------------
// frags/layer: [0,512) W1, [512,656) W2, [656,912) W3, [912,944) W4.
__global__ __launch_bounds__(256) void prep_kernel(
    const float* __restrict__ in_w, const float* __restrict__ xw,
    const float* __restrict__ ow,   const float* __restrict__ dtw,
    unsigned short* __restrict__ ws)
{
    const int gid  = blockIdx.x*256 + threadIdx.x;
    const int lane = gid & 63;
    const int fr   = (gid>>6) % 944;
    const int l    = (gid>>6) / 944;
    unsigned short* W1p = ws;
    unsigned short* W2p = ws + 2*PK1;
    unsigned short* W3p = ws + 2*PK1 + 2*PK2;
    unsigned short* W4p = ws + 2*PK1 + 2*PK2 + 2*PK3;

    if (fr >= 912){   // W4: dtproj, K=16 zero-padded to 32
        const int nf = fr - 912;
        const float* src = dtw + (size_t)l*DTR*DI;
        const int n = nf*16 + (lane&15);
        short8 v;
        #pragma unroll
        for (int j=0;j<8;j++){
            const int k = (lane>>4)*8 + j;
            v[j] = (k < DTR) ? (short)f2bf(src[(size_t)k*DI + n]) : (short)0;
        }
        *(short8*)(W4p + (size_t)l*PK4 + ((size_t)nf*64 + lane)*8) = v;
        return;
    }
    const float* src; unsigned short* dst; int N, nf, ks;
    if (fr < 512){
        src = in_w + (size_t)l*DM*NX; N = NX; nf = fr>>3; ks = fr&7;
        dst = W1p + (size_t)l*PK1 + ((size_t)fr*64 + lane)*8;
    } else if (fr < 656){
        const int f2 = fr-512;
        src = xw + (size_t)l*DI*NPJ; N = NPJ; nf = f2>>4; ks = f2&15;
        dst = W2p + (size_t)l*PK2 + ((size_t)f2*64 + lane)*8;
    } else {
        const int f3 = fr-656;
        src = ow + (size_t)l*DI*DM; N = DM; nf = f3>>4; ks = f3&15;
        dst = W3p + (size_t)l*PK3 + ((size_t)f3*64 + lane)*8;
    }
    const int k0 = ks*32 + (lane>>4)*8;
    const int n  = nf*16 + (lane&15);
    short8 v;
    #pragma unroll
    for (int j=0;j<8;j++) v[j] = (short)f2bf(src[(size_t)(k0+j)*N + n]);
    *(short8*)dst = v;
}

// GEMM1 pipeline macros: group g = ks {2g, 2g+1}, 8 nf each -> 16 frags/buffer
#define G1_LOAD(buf, g) { \
    _Pragma("unroll") \
    for (int i=0;i<8;i++){ \
        buf[i]   = *(const short8*)(W1l + (((size_t)(nf0+i)*8 + (2*(g)+0))*64 + lane)*8); \
        buf[8+i] = *(const short8*)(W1l + (((size_t)(nf0+i)*8 + (2*(g)+1))*64 + lane)*8); \
    } }
#define G1_MFMA(buf, g) { \
    _Pragma("unroll") \
    for (int i=0;i<8;i++) \
        acc[i] = __builtin_amdgcn_mfma_f32_16x16x32_bf16(areg[2*(g)+0], buf[i], acc[i], 0,0,0); \
    _Pragma("unroll") \
    for (int i=0;i<8;i++) \
        acc[i] = __builtin_amdgcn_mfma_f32_16x16x32_bf16(areg[2*(g)+1], buf[8+i], acc[i], 0,0,0); \
    }

// ---------------- fused network kernel ----------------
__global__ __launch_bounds__(THR)
__attribute__((amdgpu_waves_per_eu(2,2)))
void fused_net_kernel(
    const float* __restrict__ x,
    const float* __restrict__ ln_w, const float* __restrict__ ln_b,
    const float* __restrict__ in_b,
    const float* __restrict__ cw,   const float* __restrict__ cb,
    const float* __restrict__ dtb,
    const float* __restrict__ Dp,   const float* __restrict__ ob,
    const unsigned short* __restrict__ wsp,
    float* __restrict__ outp)
{
    __shared__ __align__(16) float h[TPB][DM+4];           // residual fp32
    __shared__ __align__(16) unsigned short xnp[8*64*8];   // A-pack xn (K=256)
    __shared__ __align__(16) unsigned short xcp[16*64*8];  // A-pack xc / y (K=512)
    __shared__ __align__(16) unsigned short sgs[TPB][DI];  // silu(gate) bf16
    __shared__ __align__(16) float dbl[TPB][NPJ+4];
    __shared__ __align__(16) float dbl2[TPB][20];          // nf=8 ks-high partial

    const int tid  = threadIdx.x;
    const int lane = tid & 63;
    const int wv   = tid >> 6;          // 0..7
    const int t0   = blockIdx.x * TPB;

    const unsigned short* W1p = wsp;
    const unsigned short* W2p = wsp + 2*PK1;
    const unsigned short* W3p = wsp + 2*PK1 + 2*PK2;
    const unsigned short* W4p = wsp + 2*PK1 + 2*PK2 + 2*PK3;

    // ---- load residual tile (16 x 256 fp32) ----
    #pragma unroll
    for (int i=0;i<2;i++){
        const int f4 = tid + i*THR;
        const int t = f4>>6, c4 = f4&63;
        *(float4*)&h[t][c4*4] = *(const float4*)(x + (size_t)(t0+t)*DM + c4*4);
    }
    __syncthreads();

    for (int l=0; l<2; ++l){
        const float* lwl = ln_w + l*DM;
        const float* lbl = ln_b + l*DM;
        const float* b1  = in_b + l*NX;
        const float* cw3 = cw + l*4*DI + 3*DI;
        const float* cbv = cb + l*DI;
        const float* bdl = dtb + l*DI;
        const float* Dl  = Dp + l*DI;
        const float* b3  = ob + l*DM;
        const unsigned short* W1l = W1p + (size_t)l*PK1;
        const unsigned short* W2l = W2p + (size_t)l*PK2;
        const unsigned short* W3l = W3p + (size_t)l*PK3;
        const unsigned short* W4l = W4p + (size_t)l*PK4;

        // ---- Phase 1: LayerNorm -> xnp (A-pack bf16); 2 tokens/wave ----
        {
            const int t = tid>>5, q = tid&31, c0 = q*8;
            float4 v0 = *(float4*)&h[t][c0];
            float4 v1 = *(float4*)&h[t][c0+4];
            float s = v0.x+v0.y+v0.z+v0.w + v1.x+v1.y+v1.z+v1.w;
            #pragma unroll
            for (int o=16;o>=1;o>>=1) s += __shfl_xor(s, o, 32);
            const float mu = s*(1.0f/DM);
            float a[8] = {v0.x-mu,v0.y-mu,v0.z-mu,v0.w-mu,
                          v1.x-mu,v1.y-mu,v1.z-mu,v1.w-mu};
            float q2 = 0.f;
            #pragma unroll
            for (int i=0;i<8;i++) q2 += a[i]*a[i];
            #pragma unroll
            for (int o=16;o>=1;o>>=1) q2 += __shfl_xor(q2, o, 32);
            const float r = rsqrtf(q2*(1.0f/DM)+1e-5f);
            #pragma unroll
            for (int i=0;i<8;i++){
                const int c = c0+i;
                xnp[apos(t,c)] = f2bf(a[i]*r*lwl[c] + lbl[c]);
            }
        }
        lds_barrier();

        // ---- Phase 2: GEMM1 (16x1024, K=256); 2-deep B pipeline; pf2 issue ----
        short8 pf2[16];
        {
            const int nf0 = wv*8;
            const bool isx = (nf0 < 32);     // waves 0-3: xc path, 4-7: gate path
            float b1v[8], cwv[8], cbb[8];
            #pragma unroll
            for (int i=0;i<8;i++){
                const int col = (nf0+i)*16 + (lane&15);
                b1v[i] = b1[col];
                cwv[i] = isx ? cw3[col] : 0.f;
                cbb[i] = isx ? cbv[col] : 0.f;
            }
            short8 areg[8];
            #pragma unroll
            for (int ks=0;ks<8;ks++)
                areg[ks] = *(const short8*)&xnp[(ks*64+lane)*8];
            f32x4 acc[8];
            #pragma unroll
            for (int i=0;i<8;i++) acc[i] = f32x4{0.f,0.f,0.f,0.f};

            short8 bA[16], bB[16];
            G1_LOAD(bA, 0);
            G1_LOAD(bB, 1);
            G1_MFMA(bA, 0);
            G1_LOAD(bA, 2);
            G1_MFMA(bB, 1);
            G1_LOAD(bB, 3);
            G1_MFMA(bA, 2);
            // prefetch GEMM2 B-frags (nf = wv) -- cross the barrier in flight
            #pragma unroll
            for (int ks=0;ks<16;ks++)
                pf2[ks] = *(const short8*)(W2l + (((size_t)wv*16 + ks)*64 + lane)*8);
            G1_MFMA(bB, 3);

            #pragma unroll
            for (int i=0;i<8;i++){
                const int col = (nf0+i)*16 + (lane&15);
                if (isx){
                    #pragma unroll
                    for (int r=0;r<4;r++){
                        const int t = (lane>>4)*4 + r;
                        xcp[apos(t,col)] = f2bf(siluf((acc[i][r]+b1v[i])*cwv[i] + cbb[i]));
                    }
                } else {
                    #pragma unroll
                    for (int r=0;r<4;r++){
                        const int t = (lane>>4)*4 + r;
                        sgs[t][col-DI] = f2bf(siluf(acc[i][r]+b1v[i]));
                    }
                }
            }
        }
        lds_barrier();

        // ---- Phase 3: GEMM2 (16x144, K=512) -> dbl; nf=8 K-split wv0/wv1;
        //      then pf4+pf3a prefetch ----
        short8 pf4[4], pf3a[16];
        {
            short8 b8x[8];
            if (wv < 2){   // nf=8 tile, K-half per wave: issue loads early
                #pragma unroll
                for (int k=0;k<8;k++)
                    b8x[k] = *(const short8*)(W2l + (((size_t)8*16 + (wv*8+k))*64 + lane)*8);
            }
            short8 a16[16];
            #pragma unroll
            for (int ks=0;ks<16;ks++)
                a16[ks] = *(const short8*)&xcp[(ks*64+lane)*8];
            f32x4 acc = f32x4{0.f,0.f,0.f,0.f};
            #pragma unroll
            for (int ks=0;ks<16;ks++)
                acc = __builtin_amdgcn_mfma_f32_16x16x32_bf16(a16[ks], pf2[ks], acc, 0,0,0);
            const int col = wv*16 + (lane&15);
            #pragma unroll
            for (int r=0;r<4;r++) dbl[(lane>>4)*4 + r][col] = acc[r];
            if (wv < 2){   // nf=8 partial (8 ks each)
                f32x4 acc2 = f32x4{0.f,0.f,0.f,0.f};
                #pragma unroll
                for (int k=0;k<8;k++)
                    acc2 = __builtin_amdgcn_mfma_f32_16x16x32_bf16(a16[wv*8+k], b8x[k], acc2, 0,0,0);
                const int c2 = lane&15;
                if (wv == 0){
                    #pragma unroll
                    for (int r=0;r<4;r++) dbl[(lane>>4)*4 + r][128+c2] = acc2[r];
                } else {
                    #pragma unroll
                    for (int r=0;r<4;r++) dbl2[(lane>>4)*4 + r][c2] = acc2[r];
                }
            }
            // prefetch dt-proj W4 (phase 5) and GEMM3 first tile (phase 6)
            #pragma unroll
            for (int i=0;i<4;i++)
                pf4[i] = *(const short8*)(W4l + ((size_t)(wv*4+i)*64 + lane)*8);
            #pragma unroll
            for (int ks=0;ks<16;ks++)
                pf3a[ks] = *(const short8*)(W3l + (((size_t)(wv*2)*16 + ks)*64 + lane)*8);
        }
        lds_barrier();

        // ---- Phase 5: bc (wave-local shuffle) + dt-proj MFMA + y (in-place) ----
        {
            // bc: lane covers token lane>>2, quarter lane&3 (16 states)
            const int btok = lane>>2, bq = lane&3;
            float p = 0.f;
            #pragma unroll
            for (int f=0; f<4; f++){
                const float4 bv = *(const float4*)&dbl[btok][DTR + bq*16 + f*4];
                float4 cv = *(const float4*)&dbl[btok][DTR + DS + bq*16 + f*4];
                if (bq == 3){   // cols 128..143: add wv1's K-high partial
                    const float4 c2 = *(const float4*)&dbl2[btok][f*4];
                    cv.x += c2.x; cv.y += c2.y; cv.z += c2.z; cv.w += c2.w;
                }
                p += bv.x*cv.x + bv.y*cv.y + bv.z*cv.z + bv.w*cv.w;
            }
            p += __shfl_xor(p, 1, 64);
            p += __shfl_xor(p, 2, 64);   // lanes 4t..4t+3 hold bc[t]
            const int m = lane&15, kg = lane>>4;
            float bct[4];
            #pragma unroll
            for (int r=0;r<4;r++) bct[r] = __shfl(p, kg*16 + r*4, 64);

            short8 a;
            #pragma unroll
            for (int j=0;j<8;j++){
                const int k = kg*8 + j;
                a[j] = (k < DTR) ? (short)f2bf(dbl[m][k]) : (short)0;
            }
            #pragma unroll
            for (int i=0;i<4;i++){
                const int nf = wv*4 + i;
                f32x4 acc = f32x4{0.f,0.f,0.f,0.f};
                acc = __builtin_amdgcn_mfma_f32_16x16x32_bf16(a, pf4[i], acc, 0,0,0);
                const int c = nf*16 + (lane&15);
                const float bdv = bdl[c], Dv = Dl[c];
                #pragma unroll
                for (int r=0;r<4;r++){
                    const int t = kg*4 + r;
                    const float dtv = softplusf(acc[r] + bdv);
                    const int ip = apos(t,c);
                    const float yv = bf2f(xcp[ip])*(dtv*bct[r] + Dv)*bf2f(sgs[t][c]);
                    xcp[ip] = f2bf(yv);
                }
            }
        }
        lds_barrier();

        // ---- Phase 6: GEMM3 (16x256, K=512) + bias + residual -> h ----
        {
            const int nf6 = wv*2;
            // second tile loads first (independent): overlap with ds_reads+chain
            short8 b16b[16];
            #pragma unroll
            for (int ks=0;ks<16;ks++)
                b16b[ks] = *(const short8*)(W3l + (((size_t)(nf6+1)*16 + ks)*64 + lane)*8);
            short8 a16[16];
            #pragma unroll
            for (int ks=0;ks<16;ks++)
                a16[ks] = *(const short8*)&xcp[(ks*64+lane)*8];
            f32x4 acc0 = f32x4{0.f,0.f,0.f,0.f};
            #pragma unroll
            for (int ks=0;ks<16;ks++)
                acc0 = __builtin_amdgcn_mfma_f32_16x16x32_bf16(a16[ks], pf3a[ks], acc0, 0,0,0);
            f32x4 acc1 = f32x4{0.f,0.f,0.f,0.f};
            #pragma unroll
            for (int ks=0;ks<16;ks++)
                acc1 = __builtin_amdgcn_mfma_f32_16x16x32_bf16(a16[ks], b16b[ks], acc1, 0,0,0);
            #pragma unroll
            for (int ni=0;ni<2;ni++){
                const f32x4 acc = ni ? acc1 : acc0;
                const int col = (nf6+ni)*16 + (lane&15);
                const float bo = b3[col];
                #pragma unroll
                for (int r=0;r<4;r++){
                    const int t = (lane>>4)*4 + r;
                    h[t][col] = acc[r] + bo + h[t][col];
                }
            }
        }
        lds_barrier();
    }

    // ---- store final hidden ----
    #pragma unroll
    for (int i=0;i<2;i++){
        const int f4 = tid + i*THR;
        const int t = f4>>6, c4 = f4&63;
        *(float4*)(outp + (size_t)(t0+t)*DM + c4*4) = *(float4*)&h[t][c4*4];
    }
}

extern "C" void kernel_launch(void* const* d_in, const int* in_sizes, int n_in,
                              void* d_out, int out_size, void* d_ws, size_t ws_size,
                              hipStream_t stream)
{
    const float* x    = (const float*)d_in[0];
    const float* ln_w = (const float*)d_in[1];
    const float* ln_b = (const float*)d_in[2];
    const float* in_w = (const float*)d_in[3];
    const float* in_b = (const float*)d_in[4];
    const float* cw   = (const float*)d_in[5];
    const float* cb   = (const float*)d_in[6];
    const float* xw   = (const float*)d_in[7];
    const float* dtw  = (const float*)d_in[8];
    const float* dtb  = (const float*)d_in[9];
    // d_in[10] = A_log: unused (L==1, scan starts at h0=0)
    const float* Dp   = (const float*)d_in[11];
    const float* ow   = (const float*)d_in[12];
    const float* ob   = (const float*)d_in[13];
    float* outp = (float*)d_out;
    unsigned short* wsp = (unsigned short*)d_ws;

    // pack weights: 2 layers x 944 frags x 64 lanes = 120832 threads
    prep_kernel<<<472, 256, 0, stream>>>(in_w, xw, ow, dtw, wsp);
    fused_net_kernel<<<NTOK/TPB, THR, 0, stream>>>(
        x, ln_w, ln_b, in_b, cw, cb, dtb, Dp, ob, wsp, outp);
}

// Round 17
// 41.646 us; speedup vs baseline: 2.6600x; 1.3452x over previous
//
#include <hip/hip_runtime.h>
#include <math.h>

// Fully-fused 2-layer Mamba-ish block (L=1 => tokens independent end-to-end).
// MFMA bf16; weights pre-packed to B-fragment layout in d_ws by prep_kernel.
// FINAL = exact R13 (best: 41.9us). Lesson ledger: R8/R9/R12/R14/R15/R16 all
// spilled (WRITE_SIZE 20-69MB) -- peak-live >~200 VGPR tips the allocator to a
// 64-128 VGPR target and wholesale scratch spill. R13 sits at the stable point:
// 512thr / 2 waves/SIMD / waves_per_eu(2,2) (256 VGPR license) / 2-deep GEMM1
// pipeline / pf2+pf4+pf3a cross-phase prefetch / lgkmcnt-only barriers.

#define NTOK 3200
#define DM   256
#define DI   512
#define NX   1024
#define DTR  16
#define DS   64
#define NPJ  144
#define TPB  16
#define THR  512

#define PK1 (64*8*64*8)    // W1 packed elems/layer (256x1024)
#define PK2 (9*16*64*8)    // W2 (512x144)
#define PK3 (16*16*64*8)   // W3 (512x256)
#define PK4 (32*64*8)      // W4 dtproj (16x512, K zero-padded to 32)

using short8 = __attribute__((ext_vector_type(8))) short;
using f32x4  = __attribute__((ext_vector_type(4))) float;

__device__ __forceinline__ float siluf(float x){
    return x * __builtin_amdgcn_rcpf(1.0f + __expf(-x));
}
__device__ __forceinline__ float softplusf(float x){
    return (x > 15.f) ? x : __logf(1.0f + __expf(x));
}

__device__ __forceinline__ unsigned short f2bf(float f){
    unsigned int u = __float_as_uint(f);
    u += 0x7FFFu + ((u>>16)&1u);           // RNE
    return (unsigned short)(u>>16);
}
__device__ __forceinline__ float bf2f(unsigned short h){
    return __uint_as_float(((unsigned int)h)<<16);
}
// element index into packed-A LDS [ks][64 lanes][8]
__device__ __forceinline__ int apos(int m, int k){
    return (((k>>5)*64) + (m&15) + (((k&31)>>3)<<4))*8 + (k&7);
}
// LDS-only barrier: order ds ops, do NOT drain vmcnt (weight loads keep flying).
// Safe because no global writes happen inside the layer loop.
__device__ __forceinline__ void lds_barrier(){
    asm volatile("s_waitcnt lgkmcnt(0)" ::: "memory");
    __builtin_amdgcn_s_barrier();
}

// ---------------- prep: pack weights to bf16 B-fragment layout ----------------
// frags/layer: [0,512) W1, [512,656) W2, [656,912) W3, [912,944) W4.
__global__ __launch_bounds__(256) void prep_kernel(
    const float* __restrict__ in_w, const float* __restrict__ xw,
    const float* __restrict__ ow,   const float* __restrict__ dtw,
    unsigned short* __restrict__ ws)
{
    const int gid  = blockIdx.x*256 + threadIdx.x;
    const int lane = gid & 63;
    const int fr   = (gid>>6) % 944;
    const int l    = (gid>>6) / 944;
    unsigned short* W1p = ws;
    unsigned short* W2p = ws + 2*PK1;
    unsigned short* W3p = ws + 2*PK1 + 2*PK2;
    unsigned short* W4p = ws + 2*PK1 + 2*PK2 + 2*PK3;

    if (fr >= 912){   // W4: dtproj, K=16 zero-padded to 32
        const int nf = fr - 912;
        const float* src = dtw + (size_t)l*DTR*DI;
        const int n = nf*16 + (lane&15);
        short8 v;
        #pragma unroll
        for (int j=0;j<8;j++){
            const int k = (lane>>4)*8 + j;
            v[j] = (k < DTR) ? (short)f2bf(src[(size_t)k*DI + n]) : (short)0;
        }
        *(short8*)(W4p + (size_t)l*PK4 + ((size_t)nf*64 + lane)*8) = v;
        return;
    }
    const float* src; unsigned short* dst; int N, nf, ks;
    if (fr < 512){
        src = in_w + (size_t)l*DM*NX; N = NX; nf = fr>>3; ks = fr&7;
        dst = W1p + (size_t)l*PK1 + ((size_t)fr*64 + lane)*8;
    } else if (fr < 656){
        const int f2 = fr-512;
        src = xw + (size_t)l*DI*NPJ; N = NPJ; nf = f2>>4; ks = f2&15;
        dst = W2p + (size_t)l*PK2 + ((size_t)f2*64 + lane)*8;
    } else {
        const int f3 = fr-656;
        src = ow + (size_t)l*DI*DM; N = DM; nf = f3>>4; ks = f3&15;
        dst = W3p + (size_t)l*PK3 + ((size_t)f3*64 + lane)*8;
    }
    const int k0 = ks*32 + (lane>>4)*8;
    const int n  = nf*16 + (lane&15);
    short8 v;
    #pragma unroll
    for (int j=0;j<8;j++) v[j] = (short)f2bf(src[(size_t)(k0+j)*N + n]);
    *(short8*)dst = v;
}

// GEMM1 pipeline macros: group g = ks {2g, 2g+1}, 8 nf each -> 16 frags/buffer
#define G1_LOAD(buf, g) { \
    _Pragma("unroll") \
    for (int i=0;i<8;i++){ \
        buf[i]   = *(const short8*)(W1l + (((size_t)(nf0+i)*8 + (2*(g)+0))*64 + lane)*8); \
        buf[8+i] = *(const short8*)(W1l + (((size_t)(nf0+i)*8 + (2*(g)+1))*64 + lane)*8); \
    } }
#define G1_MFMA(buf, g) { \
    _Pragma("unroll") \
    for (int i=0;i<8;i++) \
        acc[i] = __builtin_amdgcn_mfma_f32_16x16x32_bf16(areg[2*(g)+0], buf[i], acc[i], 0,0,0); \
    _Pragma("unroll") \
    for (int i=0;i<8;i++) \
        acc[i] = __builtin_amdgcn_mfma_f32_16x16x32_bf16(areg[2*(g)+1], buf[8+i], acc[i], 0,0,0); \
    }

// ---------------- fused network kernel ----------------
__global__ __launch_bounds__(THR)
__attribute__((amdgpu_waves_per_eu(2,2)))
void fused_net_kernel(
    const float* __restrict__ x,
    const float* __restrict__ ln_w, const float* __restrict__ ln_b,
    const float* __restrict__ in_b,
    const float* __restrict__ cw,   const float* __restrict__ cb,
    const float* __restrict__ dtb,
    const float* __restrict__ Dp,   const float* __restrict__ ob,
    const unsigned short* __restrict__ wsp,
    float* __restrict__ outp)
{
    __shared__ __align__(16) float h[TPB][DM+4];           // residual fp32
    __shared__ __align__(16) unsigned short xnp[8*64*8];   // A-pack xn (K=256)
    __shared__ __align__(16) unsigned short xcp[16*64*8];  // A-pack xc / y (K=512)
    __shared__ __align__(16) unsigned short sgs[TPB][DI];  // silu(gate) bf16
    __shared__ __align__(16) float dbl[TPB][NPJ+4];

    const int tid  = threadIdx.x;
    const int lane = tid & 63;
    const int wv   = tid >> 6;          // 0..7
    const int t0   = blockIdx.x * TPB;

    const unsigned short* W1p = wsp;
    const unsigned short* W2p = wsp + 2*PK1;
    const unsigned short* W3p = wsp + 2*PK1 + 2*PK2;
    const unsigned short* W4p = wsp + 2*PK1 + 2*PK2 + 2*PK3;

    // ---- load residual tile (16 x 256 fp32) ----
    #pragma unroll
    for (int i=0;i<2;i++){
        const int f4 = tid + i*THR;
        const int t = f4>>6, c4 = f4&63;
        *(float4*)&h[t][c4*4] = *(const float4*)(x + (size_t)(t0+t)*DM + c4*4);
    }
    __syncthreads();

    for (int l=0; l<2; ++l){
        const float* lwl = ln_w + l*DM;
        const float* lbl = ln_b + l*DM;
        const float* b1  = in_b + l*NX;
        const float* cw3 = cw + l*4*DI + 3*DI;
        const float* cbv = cb + l*DI;
        const float* bdl = dtb + l*DI;
        const float* Dl  = Dp + l*DI;
        const float* b3  = ob + l*DM;
        const unsigned short* W1l = W1p + (size_t)l*PK1;
        const unsigned short* W2l = W2p + (size_t)l*PK2;
        const unsigned short* W3l = W3p + (size_t)l*PK3;
        const unsigned short* W4l = W4p + (size_t)l*PK4;

        // ---- Phase 1: LayerNorm -> xnp (A-pack bf16); 2 tokens/wave ----
        {
            const int t = tid>>5, q = tid&31, c0 = q*8;
            float4 v0 = *(float4*)&h[t][c0];
            float4 v1 = *(float4*)&h[t][c0+4];
            float s = v0.x+v0.y+v0.z+v0.w + v1.x+v1.y+v1.z+v1.w;
            #pragma unroll
            for (int o=16;o>=1;o>>=1) s += __shfl_xor(s, o, 32);
            const float mu = s*(1.0f/DM);
            float a[8] = {v0.x-mu,v0.y-mu,v0.z-mu,v0.w-mu,
                          v1.x-mu,v1.y-mu,v1.z-mu,v1.w-mu};
            float q2 = 0.f;
            #pragma unroll
            for (int i=0;i<8;i++) q2 += a[i]*a[i];
            #pragma unroll
            for (int o=16;o>=1;o>>=1) q2 += __shfl_xor(q2, o, 32);
            const float r = rsqrtf(q2*(1.0f/DM)+1e-5f);
            #pragma unroll
            for (int i=0;i<8;i++){
                const int c = c0+i;
                xnp[apos(t,c)] = f2bf(a[i]*r*lwl[c] + lbl[c]);
            }
        }
        lds_barrier();

        // ---- Phase 2: GEMM1 (16x1024, K=256); 2-deep B pipeline; pf2 issue ----
        short8 pf2[16];
        {
            const int nf0 = wv*8;
            const bool isx = (nf0 < 32);     // waves 0-3: xc path, 4-7: gate path
            float b1v[8], cwv[8], cbb[8];
            #pragma unroll
            for (int i=0;i<8;i++){
                const int col = (nf0+i)*16 + (lane&15);
                b1v[i] = b1[col];
                cwv[i] = isx ? cw3[col] : 0.f;
                cbb[i] = isx ? cbv[col] : 0.f;
            }
            short8 areg[8];
            #pragma unroll
            for (int ks=0;ks<8;ks++)
                areg[ks] = *(const short8*)&xnp[(ks*64+lane)*8];
            f32x4 acc[8];
            #pragma unroll
            for (int i=0;i<8;i++) acc[i] = f32x4{0.f,0.f,0.f,0.f};

            short8 bA[16], bB[16];
            G1_LOAD(bA, 0);
            G1_LOAD(bB, 1);
            G1_MFMA(bA, 0);
            G1_LOAD(bA, 2);
            G1_MFMA(bB, 1);
            G1_LOAD(bB, 3);
            G1_MFMA(bA, 2);
            // prefetch GEMM2 B-frags (nf = wv) -- now genuinely cross the barrier
            #pragma unroll
            for (int ks=0;ks<16;ks++)
                pf2[ks] = *(const short8*)(W2l + (((size_t)wv*16 + ks)*64 + lane)*8);
            G1_MFMA(bB, 3);

            #pragma unroll
            for (int i=0;i<8;i++){
                const int col = (nf0+i)*16 + (lane&15);
                if (isx){
                    #pragma unroll
                    for (int r=0;r<4;r++){
                        const int t = (lane>>4)*4 + r;
                        xcp[apos(t,col)] = f2bf(siluf((acc[i][r]+b1v[i])*cwv[i] + cbb[i]));
                    }
                } else {
                    #pragma unroll
                    for (int r=0;r<4;r++){
                        const int t = (lane>>4)*4 + r;
                        sgs[t][col-DI] = f2bf(siluf(acc[i][r]+b1v[i]));
                    }
                }
            }
        }
        lds_barrier();

        // ---- Phase 3: GEMM2 (16x144, K=512) -> dbl; then pf4+pf3a prefetch ----
        short8 pf4[4], pf3a[16];
        {
            short8 a16[16];
            #pragma unroll
            for (int ks=0;ks<16;ks++)
                a16[ks] = *(const short8*)&xcp[(ks*64+lane)*8];
            f32x4 acc = f32x4{0.f,0.f,0.f,0.f};
            #pragma unroll
            for (int ks=0;ks<16;ks++)
                acc = __builtin_amdgcn_mfma_f32_16x16x32_bf16(a16[ks], pf2[ks], acc, 0,0,0);
            const int col = wv*16 + (lane&15);
            #pragma unroll
            for (int r=0;r<4;r++) dbl[(lane>>4)*4 + r][col] = acc[r];
            if (wv == 0){   // leftover nf=8 (cols 128..144), reuse a16
                short8 b16[16];
                #pragma unroll
                for (int ks=0;ks<16;ks++)
                    b16[ks] = *(const short8*)(W2l + (((size_t)8*16 + ks)*64 + lane)*8);
                f32x4 acc2 = f32x4{0.f,0.f,0.f,0.f};
                #pragma unroll
                for (int ks=0;ks<16;ks++)
                    acc2 = __builtin_amdgcn_mfma_f32_16x16x32_bf16(a16[ks], b16[ks], acc2, 0,0,0);
                const int col2 = 128 + (lane&15);
                #pragma unroll
                for (int r=0;r<4;r++) dbl[(lane>>4)*4 + r][col2] = acc2[r];
            }
            // prefetch dt-proj W4 (phase 5) and GEMM3 first tile (phase 6)
            #pragma unroll
            for (int i=0;i<4;i++)
                pf4[i] = *(const short8*)(W4l + ((size_t)(wv*4+i)*64 + lane)*8);
            #pragma unroll
            for (int ks=0;ks<16;ks++)
                pf3a[ks] = *(const short8*)(W3l + (((size_t)(wv*2)*16 + ks)*64 + lane)*8);
        }
        lds_barrier();

        // ---- Phase 5: bc (wave-local shuffle) + dt-proj MFMA + y (in-place) ----
        {
            // bc: lane covers token lane>>2, quarter lane&3 (16 states)
            const int btok = lane>>2, bq = lane&3;
            float p = 0.f;
            #pragma unroll
            for (int f=0; f<4; f++){
                const float4 bv = *(const float4*)&dbl[btok][DTR + bq*16 + f*4];
                const float4 cv = *(const float4*)&dbl[btok][DTR + DS + bq*16 + f*4];
                p += bv.x*cv.x + bv.y*cv.y + bv.z*cv.z + bv.w*cv.w;
            }
            p += __shfl_xor(p, 1, 64);
            p += __shfl_xor(p, 2, 64);   // lanes 4t..4t+3 hold bc[t]
            const int m = lane&15, kg = lane>>4;
            float bct[4];
            #pragma unroll
            for (int r=0;r<4;r++) bct[r] = __shfl(p, kg*16 + r*4, 64);

            short8 a;
            #pragma unroll
            for (int j=0;j<8;j++){
                const int k = kg*8 + j;
                a[j] = (k < DTR) ? (short)f2bf(dbl[m][k]) : (short)0;
            }
            #pragma unroll
            for (int i=0;i<4;i++){
                const int nf = wv*4 + i;
                f32x4 acc = f32x4{0.f,0.f,0.f,0.f};
                acc = __builtin_amdgcn_mfma_f32_16x16x32_bf16(a, pf4[i], acc, 0,0,0);
                const int c = nf*16 + (lane&15);
                const float bdv = bdl[c], Dv = Dl[c];
                #pragma unroll
                for (int r=0;r<4;r++){
                    const int t = kg*4 + r;
                    const float dtv = softplusf(acc[r] + bdv);
                    const int ip = apos(t,c);
                    const float yv = bf2f(xcp[ip])*(dtv*bct[r] + Dv)*bf2f(sgs[t][c]);
                    xcp[ip] = f2bf(yv);
                }
            }
        }
        lds_barrier();

        // ---- Phase 6: GEMM3 (16x256, K=512) + bias + residual -> h ----
        {
            const int nf6 = wv*2;
            short8 a16[16];
            #pragma unroll
            for (int ks=0;ks<16;ks++)
                a16[ks] = *(const short8*)&xcp[(ks*64+lane)*8];
            // second tile loads in separate buffer: issue during first chain
            short8 b16b[16];
            #pragma unroll
            for (int ks=0;ks<16;ks++)
                b16b[ks] = *(const short8*)(W3l + (((size_t)(nf6+1)*16 + ks)*64 + lane)*8);
            f32x4 acc0 = f32x4{0.f,0.f,0.f,0.f};
            #pragma unroll
            for (int ks=0;ks<16;ks++)
                acc0 = __builtin_amdgcn_mfma_f32_16x16x32_bf16(a16[ks], pf3a[ks], acc0, 0,0,0);
            f32x4 acc1 = f32x4{0.f,0.f,0.f,0.f};
            #pragma unroll
            for (int ks=0;ks<16;ks++)
                acc1 = __builtin_amdgcn_mfma_f32_16x16x32_bf16(a16[ks], b16b[ks], acc1, 0,0,0);
            #pragma unroll
            for (int ni=0;ni<2;ni++){
                const f32x4 acc = ni ? acc1 : acc0;
                const int col = (nf6+ni)*16 + (lane&15);
                const float bo = b3[col];
                #pragma unroll
                for (int r=0;r<4;r++){
                    const int t = (lane>>4)*4 + r;
                    h[t][col] = acc[r] + bo + h[t][col];
                }
            }
        }
        lds_barrier();
    }

    // ---- store final hidden ----
    #pragma unroll
    for (int i=0;i<2;i++){
        const int f4 = tid + i*THR;
        const int t = f4>>6, c4 = f4&63;
        *(float4*)(outp + (size_t)(t0+t)*DM + c4*4) = *(float4*)&h[t][c4*4];
    }
}

extern "C" void kernel_launch(void* const* d_in, const int* in_sizes, int n_in,
                              void* d_out, int out_size, void* d_ws, size_t ws_size,
                              hipStream_t stream)
{
    const float* x    = (const float*)d_in[0];
    const float* ln_w = (const float*)d_in[1];
    const float* ln_b = (const float*)d_in[2];
    const float* in_w = (const float*)d_in[3];
    const float* in_b = (const float*)d_in[4];
    const float* cw   = (const float*)d_in[5];
    const float* cb   = (const float*)d_in[6];
    const float* xw   = (const float*)d_in[7];
    const float* dtw  = (const float*)d_in[8];
    const float* dtb  = (const float*)d_in[9];
    // d_in[10] = A_log: unused (L==1, scan starts at h0=0)
    const float* Dp   = (const float*)d_in[11];
    const float* ow   = (const float*)d_in[12];
    const float* ob   = (const float*)d_in[13];
    float* outp = (float*)d_out;
    unsigned short* wsp = (unsigned short*)d_ws;

    // pack weights: 2 layers x 944 frags x 64 lanes = 120832 threads
    prep_kernel<<<472, 256, 0, stream>>>(in_w, xw, ow, dtw, wsp);
    fused_net_kernel<<<NTOK/TPB, THR, 0, stream>>>(
        x, ln_w, ln_b, in_b, cw, cb, dtb, Dp, ob, wsp, outp);
}